// Round 4
// baseline (939.976 us; speedup 1.0000x reference)
//
#include <hip/hip_runtime.h>
#include <math.h>

#define BN 512
#define DN 256
#define KN 65536
#define CN 1000
#define EQ_CAP 512
#define EPSTR 136     // padded epilogue LDS stride (ushorts) in gemm_sim
#define DCSPLIT 32    // k-splits for dc gemm

typedef __attribute__((ext_vector_type(8))) short bf16x8;
typedef __attribute__((ext_vector_type(4))) float f32x4;

__device__ __forceinline__ unsigned short f2bf(float f) {
    unsigned u = __float_as_uint(f);
    unsigned r = (u + 0x7FFFu + ((u >> 16) & 1u)) >> 16;
    return (unsigned short)r;
}
__device__ __forceinline__ float bf2f(unsigned short h) {
    return __uint_as_float(((unsigned)h) << 16);
}
__device__ __forceinline__ unsigned fkey16(unsigned b) {
    b &= 0xFFFFu;
    return (b & 0x8000u) ? ((~b) & 0xFFFFu) : (b | 0x8000u);
}
__device__ __forceinline__ void async16(const void* g, void* l) {
    __builtin_amdgcn_global_load_lds(
        (const __attribute__((address_space(1))) unsigned*)g,
        (__attribute__((address_space(3))) unsigned*)l, 16, 0, 0);
}

// ---- fp32 -> bf16 convert (norm_q / k_feat into Acat halves) ----
__global__ void __launch_bounds__(256) cvt_bf16(const float* __restrict__ in,
                                                unsigned short* __restrict__ out) {
    int i = (blockIdx.x * 256 + threadIdx.x) * 4;
    float4 v = *(const float4*)&in[i];
    ushort4 o;
    o.x = f2bf(v.x); o.y = f2bf(v.y); o.z = f2bf(v.z); o.w = f2bf(v.w);
    *(ushort4*)&out[i] = o;
}

// ---- queue [256,65536] f32 -> queueT [65536,256] bf16 ----
__global__ void __launch_bounds__(256) transpose_q(const float* __restrict__ Q,
                                                   unsigned short* __restrict__ Qt) {
    __shared__ float T[64][65];
    int tid = threadIdx.x;
    int n0 = blockIdx.x * 64;
    int d0 = blockIdx.y * 64;
    #pragma unroll
    for (int i = 0; i < 4; ++i) {
        int flat = i * 256 + tid;
        int d = flat >> 4, nq = (flat & 15) * 4;
        float4 v = *(const float4*)&Q[(size_t)(d0 + d) * KN + n0 + nq];
        T[d][nq] = v.x; T[d][nq + 1] = v.y; T[d][nq + 2] = v.z; T[d][nq + 3] = v.w;
    }
    __syncthreads();
    int n = tid >> 2, dbase = (tid & 3) * 16;
    unsigned u[8];
    #pragma unroll
    for (int j = 0; j < 8; ++j) {
        unsigned short a = f2bf(T[dbase + 2 * j][n]);
        unsigned short b = f2bf(T[dbase + 2 * j + 1][n]);
        u[j] = (unsigned)a | ((unsigned)b << 16);
    }
    unsigned short* o = &Qt[(size_t)(n0 + n) * DN + d0 + dbase];
    *(uint4*)o = make_uint4(u[0], u[1], u[2], u[3]);
    *(uint4*)(o + 8) = make_uint4(u[4], u[5], u[6], u[7]);
}

// ---- MFMA GEMM, swapped operands, LDS-transposed coalesced epilogue.
// Blocks with blockIdx.y >= mBlockSplit apply exp(10x) and accumulate row sums.
__global__ void __launch_bounds__(256) gemm_sim(const unsigned short* __restrict__ A,
                                                const unsigned short* __restrict__ Bt,
                                                unsigned short* __restrict__ simOut,
                                                unsigned short* __restrict__ expOut,
                                                float* __restrict__ Zb,
                                                int mBlockSplit) {
    __shared__ unsigned short smem[128 * 64 * 2];   // As | Bs, reused as epilogue buf
    __shared__ float Zred[128];
    unsigned short* As = smem;
    unsigned short* Bs = smem + 128 * 64;
    int tid = threadIdx.x;
    int n0 = blockIdx.x * 128, m0 = blockIdx.y * 128;
    bool isExp = ((int)blockIdx.y >= mBlockSplit);
    int lane = tid & 63, w = tid >> 6;
    int l15 = lane & 15, quad = lane >> 4;
    int wm = w & 1, wn = w >> 1;
    f32x4 acc[4][4];   // [mi][ni]; D layout: col(l15)=m, row(quad*4+reg)=n
    #pragma unroll
    for (int mi = 0; mi < 4; ++mi)
        #pragma unroll
        for (int ni = 0; ni < 4; ++ni)
            #pragma unroll
            for (int j = 0; j < 4; ++j) acc[mi][ni][j] = 0.f;

    for (int k0 = 0; k0 < DN; k0 += 64) {
        #pragma unroll
        for (int i = 0; i < 4; ++i) {
            int f = (i * 256 + tid) * 8;
            async16(A + (size_t)(m0 + (f >> 6)) * DN + k0 + (f & 63), &As[f]);
        }
        #pragma unroll
        for (int i = 0; i < 4; ++i) {
            int f = (i * 256 + tid) * 8;
            async16(Bt + (size_t)(n0 + (f >> 6)) * DN + k0 + (f & 63), &Bs[f]);
        }
        __syncthreads();
        #pragma unroll
        for (int ks = 0; ks < 2; ++ks) {
            bf16x8 am[4], bn[4];
            #pragma unroll
            for (int mi = 0; mi < 4; ++mi)
                am[mi] = *(const bf16x8*)&As[(wm * 64 + mi * 16 + l15) * 64 + ks * 32 + quad * 8];
            #pragma unroll
            for (int ni = 0; ni < 4; ++ni)
                bn[ni] = *(const bf16x8*)&Bs[(wn * 64 + ni * 16 + l15) * 64 + ks * 32 + quad * 8];
            #pragma unroll
            for (int mi = 0; mi < 4; ++mi)
                #pragma unroll
                for (int ni = 0; ni < 4; ++ni)
                    acc[mi][ni] = __builtin_amdgcn_mfma_f32_16x16x32_bf16(bn[ni], am[mi], acc[mi][ni], 0, 0, 0);
        }
        __syncthreads();
    }

    unsigned short* obase = isExp ? expOut : simOut;
    int orow0 = isExp ? (m0 - mBlockSplit * 128) : m0;
    float rsum[4] = {0.f, 0.f, 0.f, 0.f};

    #pragma unroll
    for (int round = 0; round < 2; ++round) {
        if (wm == round) {
            #pragma unroll
            for (int mi = 0; mi < 4; ++mi) {
                int mrow = mi * 16 + l15;
                #pragma unroll
                for (int ni = 0; ni < 4; ++ni) {
                    int nc = wn * 64 + ni * 16 + quad * 4;
                    float v0 = acc[mi][ni][0], v1 = acc[mi][ni][1];
                    float v2 = acc[mi][ni][2], v3 = acc[mi][ni][3];
                    if (isExp) {
                        v0 = __expf(v0 * 10.0f); v1 = __expf(v1 * 10.0f);
                        v2 = __expf(v2 * 10.0f); v3 = __expf(v3 * 10.0f);
                    }
                    unsigned short u0 = f2bf(v0), u1 = f2bf(v1), u2 = f2bf(v2), u3 = f2bf(v3);
                    if (isExp) rsum[mi] += bf2f(u0) + bf2f(u1) + bf2f(u2) + bf2f(u3);
                    *(uint2*)&smem[mrow * EPSTR + nc] =
                        make_uint2((unsigned)u0 | ((unsigned)u1 << 16),
                                   (unsigned)u2 | ((unsigned)u3 << 16));
                }
            }
        }
        __syncthreads();
        #pragma unroll
        for (int j = 0; j < 4; ++j) {
            int fc = j * 256 + tid;
            int mr = fc >> 4;
            int ch = fc & 15;
            uint4 val = *(uint4*)&smem[mr * EPSTR + ch * 8];
            int g = orow0 + round * 64 + mr;
            *(uint4*)&obase[(size_t)g * KN + n0 + ch * 8] = val;
        }
        __syncthreads();
    }

    if (isExp) {
        float v4[4];
        #pragma unroll
        for (int mi = 0; mi < 4; ++mi) {
            float v = rsum[mi];
            v += __shfl_xor(v, 16, 64);
            v += __shfl_xor(v, 32, 64);
            v4[mi] = v;
        }
        if (wn == 0 && quad == 0) {
            #pragma unroll
            for (int mi = 0; mi < 4; ++mi) Zred[wm * 64 + mi * 16 + l15] = v4[mi];
        }
        __syncthreads();
        if (wn == 1 && quad == 0) {
            #pragma unroll
            for (int mi = 0; mi < 4; ++mi) Zred[wm * 64 + mi * 16 + l15] += v4[mi];
        }
        __syncthreads();
        if (tid < 128) atomicAdd(&Zb[orow0 + tid], Zred[tid]);
    }
}

// ---- supcon: 2-pass radix select (parallel suffix scan) + fused loss ----
__global__ void __launch_bounds__(256) supcon(const unsigned short* __restrict__ sim,
                                              const int* __restrict__ qlabel,
                                              const int* __restrict__ target,
                                              const int* __restrict__ knnp,
                                              float* __restrict__ out0) {
    __shared__ unsigned hist[4][256];
    __shared__ unsigned sc[256];
    __shared__ unsigned s_sel, s_cntAbove;
    __shared__ int eqIdx[EQ_CAP];
    __shared__ unsigned eqCount;
    __shared__ float redZ[256], redN[256];
    int tid = threadIdx.x, w = tid >> 6;
    int row = blockIdx.x;
    const unsigned short* srow = sim + (size_t)row * KN;
    unsigned knn = (unsigned)*knnp;
    int tgt = target[row];
    if (tid == 0) eqCount = 0u;
    #pragma unroll
    for (int j = 0; j < 4; ++j) hist[j][tid] = 0u;
    __syncthreads();
    for (int i0 = tid * 4; i0 < KN; i0 += 1024) {
        uint2 v = *(const uint2*)&srow[i0];
        atomicAdd(&hist[w][fkey16(v.x) >> 8], 1u);
        atomicAdd(&hist[w][fkey16(v.x >> 16) >> 8], 1u);
        atomicAdd(&hist[w][fkey16(v.y) >> 8], 1u);
        atomicAdd(&hist[w][fkey16(v.y >> 16) >> 8], 1u);
    }
    __syncthreads();
    {   // parallel suffix scan, crossing detect (base = 0)
        unsigned tot = hist[0][tid] + hist[1][tid] + hist[2][tid] + hist[3][tid];
        sc[tid] = tot; __syncthreads();
        #pragma unroll
        for (int off = 1; off < 256; off <<= 1) {
            unsigned v = (tid + off < 256) ? sc[tid + off] : 0u;
            __syncthreads();
            sc[tid] += v; __syncthreads();
        }
        unsigned S = sc[tid];
        if (S >= knn && S - tot < knn) { s_sel = (unsigned)tid; s_cntAbove = S - tot; }
        __syncthreads();
    }
    unsigned selHi = s_sel;
    #pragma unroll
    for (int j = 0; j < 4; ++j) hist[j][tid] = 0u;
    __syncthreads();
    for (int i0 = tid * 4; i0 < KN; i0 += 1024) {
        uint2 v = *(const uint2*)&srow[i0];
        unsigned k0 = fkey16(v.x), k1 = fkey16(v.x >> 16), k2 = fkey16(v.y), k3 = fkey16(v.y >> 16);
        if ((k0 >> 8) == selHi) atomicAdd(&hist[w][k0 & 255u], 1u);
        if ((k1 >> 8) == selHi) atomicAdd(&hist[w][k1 & 255u], 1u);
        if ((k2 >> 8) == selHi) atomicAdd(&hist[w][k2 & 255u], 1u);
        if ((k3 >> 8) == selHi) atomicAdd(&hist[w][k3 & 255u], 1u);
    }
    __syncthreads();
    {   // suffix scan with base = count strictly above selHi byte
        unsigned base = s_cntAbove;
        unsigned tot = hist[0][tid] + hist[1][tid] + hist[2][tid] + hist[3][tid];
        sc[tid] = tot; __syncthreads();
        #pragma unroll
        for (int off = 1; off < 256; off <<= 1) {
            unsigned v = (tid + off < 256) ? sc[tid + off] : 0u;
            __syncthreads();
            sc[tid] += v; __syncthreads();
        }
        unsigned S = base + sc[tid];
        if (S >= knn && S - tot < knn) {
            s_sel = (selHi << 8) | (unsigned)tid;
            s_cntAbove = S - tot;
        }
        __syncthreads();
    }
    unsigned tu = s_sel;
    unsigned cgt = s_cntAbove;
    const float invT = 1.0f / 0.07f;
    float Zl = 0.f, Nl = 0.f;
    for (int i0 = tid * 4; i0 < KN; i0 += 1024) {
        uint2 v = *(const uint2*)&srow[i0];
        unsigned bits[4] = {v.x & 0xFFFFu, v.x >> 16, v.y & 0xFFFFu, v.y >> 16};
        #pragma unroll
        for (int j = 0; j < 4; ++j) {
            unsigned u = fkey16(bits[j]);
            if (u > tu) {
                float e = __expf(bf2f((unsigned short)bits[j]) * invT);
                Zl += e;
                if (qlabel[i0 + j] == tgt) Nl += e;
            } else if (u == tu) {
                unsigned pos = atomicAdd(&eqCount, 1u);
                if (pos < EQ_CAP) eqIdx[pos] = i0 + j;
            }
        }
    }
    redZ[tid] = Zl; redN[tid] = Nl;
    __syncthreads();
    for (int s = 128; s > 0; s >>= 1) {
        if (tid < s) { redZ[tid] += redZ[tid + s]; redN[tid] += redN[tid + s]; }
        __syncthreads();
    }
    if (tid == 0) {
        float Z = redZ[0], num = redN[0];
        int neq = (int)(eqCount < (unsigned)EQ_CAP ? eqCount : (unsigned)EQ_CAP);
        int needed = (int)knn - (int)cgt;
        if (needed > neq) needed = neq;
        for (int a = 1; a < neq; ++a) {
            int v = eqIdx[a]; int b2 = a - 1;
            while (b2 >= 0 && eqIdx[b2] > v) { eqIdx[b2 + 1] = eqIdx[b2]; --b2; }
            eqIdx[b2 + 1] = v;
        }
        unsigned tb = (tu & 0x8000u) ? (tu & 0x7FFFu) : ((~tu) & 0xFFFFu);
        float wt = __expf(bf2f((unsigned short)tb) * invT);
        for (int a = 0; a < needed; ++a) {
            Z += wt;
            if (qlabel[eqIdx[a]] == tgt) num += wt;
        }
        float gt = num / Z;
        if (gt > 1e-8f) atomicAdd(out0, -logf(gt) * (1.0f / (float)BN));
    }
}

// ---- dc gemm: E[512,65536]bf16 @ qlp[1000,65536]f32(->bf16)^T, split-k=32,
//      XOR-swizzled LDS (conflict-free), non-atomic split-k partials ----
__global__ void __launch_bounds__(256) dc_gemm(const unsigned short* __restrict__ E,
                                               const float* __restrict__ P,
                                               float* __restrict__ part) {
    __shared__ unsigned short As[128 * 64];   // E tile 128m x 64k, 16 KB
    __shared__ unsigned short Bs[128 * 64];   // P tile 128c x 64k, 16 KB
    int tid = threadIdx.x;
    int c0 = blockIdx.x * 128, m0 = blockIdx.y * 128;
    int kb = blockIdx.z * (KN / DCSPLIT);     // 2048 k per split
    int lane = tid & 63, w = tid >> 6;
    int l15 = lane & 15, quad = lane >> 4;
    int wm = w & 1, wc = w >> 1;
    f32x4 acc[4][4];   // [ci][mi]; D: m on l15, c on quad*4+reg
    #pragma unroll
    for (int ci = 0; ci < 4; ++ci)
        #pragma unroll
        for (int mi = 0; mi < 4; ++mi)
            #pragma unroll
            for (int j = 0; j < 4; ++j) acc[ci][mi][j] = 0.f;

    for (int kc = 0; kc < KN / DCSPLIT; kc += 64) {
        int k0 = kb + kc;
        // E tile: coalesced 16B loads, XOR-swizzled ds_write_b128
        #pragma unroll
        for (int i = 0; i < 4; ++i) {
            int f = (i * 256 + tid) * 8;       // ushort index in tile
            int er = f >> 6, ek = f & 63;      // row, k-offset
            uint4 ev = *(const uint4*)&E[(size_t)(m0 + er) * KN + k0 + ek];
            int cj = (ek >> 3) ^ (er & 7);
            *(uint4*)&As[er * 64 + cj * 8] = ev;
        }
        // P tile: coalesced float4 loads, convert, swizzled ds_write_b64
        #pragma unroll
        for (int i = 0; i < 8; ++i) {
            int f = (i * 256 + tid) * 4;       // float==ushort index in tile
            int pr = f >> 6, pk = f & 63;
            float4 pv = make_float4(0.f, 0.f, 0.f, 0.f);
            if (c0 + pr < CN) pv = *(const float4*)&P[(size_t)(c0 + pr) * KN + k0 + pk];
            unsigned lo = (unsigned)f2bf(pv.x) | ((unsigned)f2bf(pv.y) << 16);
            unsigned hi = (unsigned)f2bf(pv.z) | ((unsigned)f2bf(pv.w) << 16);
            int cj = (pk >> 3) ^ (pr & 7);
            *(uint2*)&Bs[pr * 64 + cj * 8 + (pk & 7)] = make_uint2(lo, hi);
        }
        __syncthreads();
        #pragma unroll
        for (int ks = 0; ks < 2; ++ks) {
            int sw = ((ks * 4 + quad) ^ (l15 & 7)) * 8;
            bf16x8 am[4], bc[4];
            #pragma unroll
            for (int mi = 0; mi < 4; ++mi)
                am[mi] = *(const bf16x8*)&As[(wm * 64 + mi * 16 + l15) * 64 + sw];
            #pragma unroll
            for (int ci = 0; ci < 4; ++ci)
                bc[ci] = *(const bf16x8*)&Bs[(wc * 64 + ci * 16 + l15) * 64 + sw];
            #pragma unroll
            for (int ci = 0; ci < 4; ++ci)
                #pragma unroll
                for (int mi = 0; mi < 4; ++mi)
                    acc[ci][mi] = __builtin_amdgcn_mfma_f32_16x16x32_bf16(bc[ci], am[mi], acc[ci][mi], 0, 0, 0);
        }
        __syncthreads();
    }
    // epilogue: coalesced float4 stores into split-k partials (c>=CN rows are zeros)
    float* pb = part + (size_t)blockIdx.z * (512 * 1024);
    #pragma unroll
    for (int ci = 0; ci < 4; ++ci)
        #pragma unroll
        for (int mi = 0; mi < 4; ++mi) {
            int m = m0 + wm * 64 + mi * 16 + l15;
            int c = c0 + wc * 64 + ci * 16 + quad * 4;
            *(float4*)&pb[(size_t)m * 1024 + c] =
                make_float4(acc[ci][mi][0], acc[ci][mi][1], acc[ci][mi][2], acc[ci][mi][3]);
        }
}

// ---- log_softmax(q_logits), qmask, fc loss ----
__global__ void __launch_bounds__(256) logq_fc(const float* __restrict__ x_all,
                                               const int* __restrict__ target,
                                               float* __restrict__ logq,
                                               float* __restrict__ qmask,
                                               float* __restrict__ out1) {
    int row = blockIdx.x, tid = threadIdx.x;
    const float* x = x_all + (size_t)row * CN;
    __shared__ float red[256], red2[256];
    float mx = -INFINITY, mn = INFINITY;
    for (int c = tid; c < CN; c += 256) { float v = x[c]; mx = fmaxf(mx, v); mn = fminf(mn, v); }
    red[tid] = mx; red2[tid] = mn;
    __syncthreads();
    for (int s = 128; s > 0; s >>= 1) {
        if (tid < s) { red[tid] = fmaxf(red[tid], red[tid + s]); red2[tid] = fminf(red2[tid], red2[tid + s]); }
        __syncthreads();
    }
    mx = red[0]; mn = red2[0];
    __syncthreads();
    float se = 0.f, sx = 0.f;
    for (int c = tid; c < CN; c += 256) { float v = x[c]; se += __expf(v - mx); sx += v; }
    red[tid] = se; red2[tid] = sx;
    __syncthreads();
    for (int s = 128; s > 0; s >>= 1) {
        if (tid < s) { red[tid] += red[tid + s]; red2[tid] += red2[tid + s]; }
        __syncthreads();
    }
    float lse = mx + logf(red[0]);
    float sumlogq = red2[0] - (float)CN * lse;
    for (int c = tid; c < CN; c += 256) logq[(size_t)row * CN + c] = x[c] - lse;
    if (tid == 0) {
        float lqt = x[target[row]] - lse;
        bool qm = (mn - lse) > logf(1e-8f);
        qmask[row] = qm ? 1.0f : 0.0f;
        if (qm) {
            float fc = -(0.1f / 999.0f * (sumlogq - lqt) + 0.9f * lqt);
            atomicAdd(out1, fc * (1.0f / (float)BN));
        }
    }
}

// ---- dc loss: reduce split-k partials inline, KL, masked ----
__global__ void __launch_bounds__(256) dc_loss(const float* __restrict__ part,
                                               const float* __restrict__ logq,
                                               const float* __restrict__ qmask,
                                               const float* __restrict__ Z,
                                               float* __restrict__ out2) {
    int row = blockIdx.x, tid = threadIdx.x;
    __shared__ float red[256];
    float invZ = 1.0f / Z[row];
    float s = 0.f;
    for (int c = tid; c < CN; c += 256) {
        float t = 0.f;
        #pragma unroll
        for (int sp = 0; sp < DCSPLIT; ++sp)
            t += part[(size_t)sp * (512 * 1024) + (size_t)row * 1024 + c];
        float T = t * invZ;
        if (T > 0.f) s += T * (logf(T) - logq[(size_t)row * CN + c]);
    }
    red[tid] = s;
    __syncthreads();
    for (int st = 128; st > 0; st >>= 1) {
        if (tid < st) red[tid] += red[tid + st];
        __syncthreads();
    }
    if (tid == 0 && qmask[row] > 0.f)
        atomicAdd(out2, red[0] * (1.0f / (float)BN));
}

extern "C" void kernel_launch(void* const* d_in, const int* in_sizes, int n_in,
                              void* d_out, int out_size, void* d_ws, size_t ws_size,
                              hipStream_t stream) {
    (void)in_sizes; (void)n_in; (void)out_size; (void)ws_size;
    const float* norm_q   = (const float*)d_in[0];
    const float* q_logits = (const float*)d_in[1];
    const float* k_feat   = (const float*)d_in[2];
    const float* queue    = (const float*)d_in[4];
    const float* qlp      = (const float*)d_in[5];
    const int*   qlabel   = (const int*)d_in[6];
    const int*   target   = (const int*)d_in[7];
    const int*   knnp     = (const int*)d_in[8];
    float* out = (float*)d_out;
    char* ws = (char*)d_ws;

    // layout (total ~170.3 MB; ws >= 172.4 MB proven by R3 fused run):
    // [Ebf 64M][big 64M: simBF then dc partials][queueT 32M][Acat .5M][Zb][logq][qmask]
    unsigned short* Ebf    = (unsigned short*)(ws);
    unsigned short* simBF  = (unsigned short*)(ws + 67108864);
    float*          part   = (float*)(ws + 67108864);            // overlays simBF
    unsigned short* queueT = (unsigned short*)(ws + 134217728);
    unsigned short* Acat   = (unsigned short*)(ws + 167772160);
    float* Zb    = (float*)(ws + 168296448);
    float* logq  = (float*)(ws + 168298496);
    float* qmask = (float*)(ws + 170346496);

    hipMemsetAsync(Zb, 0, 2048, stream);
    hipMemsetAsync(d_out, 0, 3 * sizeof(float), stream);

    cvt_bf16<<<dim3(128), 256, 0, stream>>>(norm_q, Acat);
    cvt_bf16<<<dim3(128), 256, 0, stream>>>(k_feat, Acat + (size_t)BN * DN);
    transpose_q<<<dim3(KN / 64, 4), 256, 0, stream>>>(queue, queueT);

    // fused sim+E gemm: y<4 -> sim rows (norm_q), y>=4 -> exp rows (k_feat)
    gemm_sim<<<dim3(KN / 128, 8), 256, 0, stream>>>(Acat, queueT, simBF, Ebf, Zb, 4);
    supcon<<<dim3(BN), 256, 0, stream>>>(simBF, qlabel, target, knnp, out + 0);
    // dc path: partials overlay simBF (dead after supcon)
    dc_gemm<<<dim3(8, 4, DCSPLIT), 256, 0, stream>>>(Ebf, qlp, part);
    logq_fc<<<dim3(BN), 256, 0, stream>>>(q_logits, target, logq, qmask, out + 1);
    dc_loss<<<dim3(BN), 256, 0, stream>>>(part, logq, qmask, Zb, out + 2);
}